// Round 2
// baseline (15943.916 us; speedup 1.0000x reference)
//
#include <hip/hip_runtime.h>
#include <math.h>

#define BB 4096
#define TT 48
#define DD 32
#define HH 256
#define G3 768
#define LL 128
#define HID 256
#define EE 8
#define NHZ 48
#define NSTEP 47
#define NTEMB (2*NSTEP+1)   // 95

__device__ __forceinline__ float sigm_f(float x) {
    return 1.0f / (1.0f + __expf(-x));
}
__device__ __forceinline__ float tanh_f(float x) {
    x = fminf(fmaxf(x, -15.0f), 15.0f);
    float e = __expf(2.0f * x);
    return (e - 1.0f) / (e + 1.0f);
}
__device__ __forceinline__ float4 axpy4(float s, float4 a, float4 z) {
    return make_float4(fmaf(s, a.x, z.x), fmaf(s, a.y, z.y),
                       fmaf(s, a.z, z.z), fmaf(s, a.w, z.w));
}

// ---------------- prep kernels ----------------

__global__ void transpose_k(const float* __restrict__ src, float* __restrict__ dst, int R, int C) {
    int i = blockIdx.x * 256 + threadIdx.x;
    if (i < R * C) {
        int r = i / C, c = i % C;
        dst[c * R + r] = src[i];   // dst is [C][R]
    }
}

__global__ void temb_k(const float* __restrict__ tproj_w, const float* __restrict__ tproj_b,
                       float* __restrict__ tembs) {
    int i = blockIdx.x * 64 + threadIdx.x;
    if (i >= NTEMB) return;
    float t = (float)i / (float)(2 * NSTEP);
    const float PI = 3.14159265358979323846f;
    float emb[8];
    #pragma unroll
    for (int m = 0; m < 4; ++m) {
        float pos = t * (float)(m + 1) * PI;
        emb[m]     = sinf(pos);
        emb[4 + m] = cosf(pos);
    }
    #pragma unroll
    for (int o = 0; o < 8; ++o) {
        float a = tproj_b[o];
        #pragma unroll
        for (int k = 0; k < 8; ++k) a = fmaf(tproj_w[o * 8 + k], emb[k], a);
        tembs[i * 8 + o] = a;
    }
}

// ---------------- GRU encoder (+ fused z0 projection) ----------------
// 16 batch rows per block, 256 threads. Thread j owns gate triplet (j, 256+j, 512+j).
// All LDS broadcasts are float4 (ds_read_b128).

__global__ __launch_bounds__(256) void gru_k(
    const float* __restrict__ Xp, const float* __restrict__ Mp,
    const float* __restrict__ w_ihT,   // [64][768]
    const float* __restrict__ w_hhT,   // [256][768]
    const float* __restrict__ b_ih, const float* __restrict__ b_hh,
    const float* __restrict__ z0_wT,   // [256][256]
    const float* __restrict__ z0_b,
    float* __restrict__ out_mean, float* __restrict__ out_lv) {

    __shared__ float h[16 * HH];     // 16KB
    __shared__ float u[16 * 64];     // 4KB
    __shared__ float obs[16];

    int tid = threadIdx.x;
    int blk = blockIdx.x;

    const float4* hq = (const float4*)h;
    const float4* uq = (const float4*)u;

    for (int e = tid; e < 16 * HH; e += 256) h[e] = 0.0f;

    float brz0 = b_ih[tid]       + b_hh[tid];
    float brz1 = b_ih[256 + tid] + b_hh[256 + tid];
    float bin_ = b_ih[512 + tid];
    float bhn_ = b_hh[512 + tid];
    __syncthreads();

    for (int t = TT - 1; t >= 0; --t) {
        // stage [X_t | mask_t] for 16 rows (one float4 per thread)
        {
            int r = tid >> 4, c4 = tid & 15;
            const float* base = (c4 < 8 ? Xp : Mp) + (size_t)(blk * 16 + r) * (TT * DD) + t * DD;
            float4 v = ((const float4*)base)[c4 & 7];
            ((float4*)u)[tid] = v;
        }
        __syncthreads();
        if (tid < 16) {
            float sm = 0.0f;
            #pragma unroll
            for (int i = 8; i < 16; ++i) {
                float4 v = uq[tid * 16 + i];
                sm += v.x + v.y + v.z + v.w;
            }
            obs[tid] = (sm > 0.0f) ? 1.0f : 0.0f;
        }

        float ar[16], az[16], an[16], ah[16];
        #pragma unroll
        for (int r = 0; r < 16; ++r) { ar[r] = brz0; az[r] = brz1; an[r] = bin_; ah[r] = bhn_; }

        // input contribution (k over 64, blocked by 4)
        for (int k4 = 0; k4 < 16; ++k4) {
            int kb = k4 * 4;
            float wr0 = w_ihT[(kb+0)*G3 + tid], wz0 = w_ihT[(kb+0)*G3 + 256 + tid], wn0 = w_ihT[(kb+0)*G3 + 512 + tid];
            float wr1 = w_ihT[(kb+1)*G3 + tid], wz1 = w_ihT[(kb+1)*G3 + 256 + tid], wn1 = w_ihT[(kb+1)*G3 + 512 + tid];
            float wr2 = w_ihT[(kb+2)*G3 + tid], wz2 = w_ihT[(kb+2)*G3 + 256 + tid], wn2 = w_ihT[(kb+2)*G3 + 512 + tid];
            float wr3 = w_ihT[(kb+3)*G3 + tid], wz3 = w_ihT[(kb+3)*G3 + 256 + tid], wn3 = w_ihT[(kb+3)*G3 + 512 + tid];
            #pragma unroll
            for (int r = 0; r < 16; ++r) {
                float4 v = uq[r * 16 + k4];
                ar[r] = fmaf(wr0, v.x, ar[r]); az[r] = fmaf(wz0, v.x, az[r]); an[r] = fmaf(wn0, v.x, an[r]);
                ar[r] = fmaf(wr1, v.y, ar[r]); az[r] = fmaf(wz1, v.y, az[r]); an[r] = fmaf(wn1, v.y, an[r]);
                ar[r] = fmaf(wr2, v.z, ar[r]); az[r] = fmaf(wz2, v.z, az[r]); an[r] = fmaf(wn2, v.z, an[r]);
                ar[r] = fmaf(wr3, v.w, ar[r]); az[r] = fmaf(wz3, v.w, az[r]); an[r] = fmaf(wn3, v.w, an[r]);
            }
        }
        // hidden contribution (k over 256, blocked by 4)
        for (int k4 = 0; k4 < 64; ++k4) {
            int kb = k4 * 4;
            float wr0 = w_hhT[(kb+0)*G3 + tid], wz0 = w_hhT[(kb+0)*G3 + 256 + tid], wn0 = w_hhT[(kb+0)*G3 + 512 + tid];
            float wr1 = w_hhT[(kb+1)*G3 + tid], wz1 = w_hhT[(kb+1)*G3 + 256 + tid], wn1 = w_hhT[(kb+1)*G3 + 512 + tid];
            float wr2 = w_hhT[(kb+2)*G3 + tid], wz2 = w_hhT[(kb+2)*G3 + 256 + tid], wn2 = w_hhT[(kb+2)*G3 + 512 + tid];
            float wr3 = w_hhT[(kb+3)*G3 + tid], wz3 = w_hhT[(kb+3)*G3 + 256 + tid], wn3 = w_hhT[(kb+3)*G3 + 512 + tid];
            #pragma unroll
            for (int r = 0; r < 16; ++r) {
                float4 v = hq[r * 64 + k4];
                ar[r] = fmaf(wr0, v.x, ar[r]); az[r] = fmaf(wz0, v.x, az[r]); ah[r] = fmaf(wn0, v.x, ah[r]);
                ar[r] = fmaf(wr1, v.y, ar[r]); az[r] = fmaf(wz1, v.y, az[r]); ah[r] = fmaf(wn1, v.y, ah[r]);
                ar[r] = fmaf(wr2, v.z, ar[r]); az[r] = fmaf(wz2, v.z, az[r]); ah[r] = fmaf(wn2, v.z, ah[r]);
                ar[r] = fmaf(wr3, v.w, ar[r]); az[r] = fmaf(wz3, v.w, az[r]); ah[r] = fmaf(wn3, v.w, ah[r]);
            }
        }

        float hnew[16], hold[16];
        #pragma unroll
        for (int r = 0; r < 16; ++r) {
            float rg = sigm_f(ar[r]);
            float zg = sigm_f(az[r]);
            float n  = tanh_f(an[r] + rg * ah[r]);
            float hv = h[r * HH + tid];
            hold[r] = hv;
            hnew[r] = (1.0f - zg) * n + zg * hv;
        }
        __syncthreads();
        #pragma unroll
        for (int r = 0; r < 16; ++r) {
            float o = obs[r];
            h[r * HH + tid] = o * hnew[r] + (1.0f - o) * hold[r];
        }
        __syncthreads();
    }

    // fused z0 projection
    float zr_[16];
    #pragma unroll
    for (int r = 0; r < 16; ++r) zr_[r] = z0_b[tid];
    for (int k4 = 0; k4 < 64; ++k4) {
        int kb = k4 * 4;
        float w0 = z0_wT[(kb+0)*256 + tid];
        float w1 = z0_wT[(kb+1)*256 + tid];
        float w2 = z0_wT[(kb+2)*256 + tid];
        float w3 = z0_wT[(kb+3)*256 + tid];
        #pragma unroll
        for (int r = 0; r < 16; ++r) {
            float4 v = hq[r * 64 + k4];
            zr_[r] = fmaf(w0, v.x, zr_[r]);
            zr_[r] = fmaf(w1, v.y, zr_[r]);
            zr_[r] = fmaf(w2, v.z, zr_[r]);
            zr_[r] = fmaf(w3, v.w, zr_[r]);
        }
    }
    int row0 = blk * 16;
    if (tid < 128) {
        #pragma unroll
        for (int r = 0; r < 16; ++r) out_mean[(row0 + r) * LL + tid] = zr_[r];
    } else {
        #pragma unroll
        for (int r = 0; r < 16; ++r) out_lv[(row0 + r) * LL + (tid - 128)] = zr_[r];
    }
}

// ---------------- ODE (RK4, 47 steps) + DeepHit head ----------------
// LDS exactly 40960B -> 4 blocks/CU. ka + cumsum in registers, head weights
// and time-embeddings straight from global (L2-resident).

__device__ __forceinline__ void ode_f(
    const float* __restrict__ in, float* __restrict__ hb, float* __restrict__ fo,
    const float* __restrict__ w1T, const float* __restrict__ w2T, const float* __restrict__ w3T,
    const float* __restrict__ temb,   // global, 8 floats
    float b1j, float b2j, float b3o, int tid) {

    const float4* inq = (const float4*)in;
    const float4* hbq = (const float4*)hb;

    // phase A: h1 = tanh([z,temb] @ w1.T + b1) -> hb[16][256]
    float tacc = 0.0f;
    #pragma unroll
    for (int k = 0; k < EE; ++k) tacc = fmaf(w1T[(LL + k) * 256 + tid], temb[k], tacc);
    float acc[16];
    #pragma unroll
    for (int r = 0; r < 16; ++r) acc[r] = b1j + tacc;
    for (int k4 = 0; k4 < 32; ++k4) {
        int kb = k4 * 4;
        float w0 = w1T[(kb+0)*256 + tid];
        float w1 = w1T[(kb+1)*256 + tid];
        float w2 = w1T[(kb+2)*256 + tid];
        float w3 = w1T[(kb+3)*256 + tid];
        #pragma unroll
        for (int r = 0; r < 16; ++r) {
            float4 v = inq[r * 32 + k4];
            acc[r] = fmaf(w0, v.x, acc[r]);
            acc[r] = fmaf(w1, v.y, acc[r]);
            acc[r] = fmaf(w2, v.z, acc[r]);
            acc[r] = fmaf(w3, v.w, acc[r]);
        }
    }
    #pragma unroll
    for (int r = 0; r < 16; ++r) hb[r * HID + tid] = tanh_f(acc[r]);
    __syncthreads();

    // phase B: h2 = tanh(h1 @ w2.T + b2)
    float a2[16];
    #pragma unroll
    for (int r = 0; r < 16; ++r) a2[r] = b2j;
    for (int k4 = 0; k4 < 64; ++k4) {
        int kb = k4 * 4;
        float w0 = w2T[(kb+0)*256 + tid];
        float w1 = w2T[(kb+1)*256 + tid];
        float w2 = w2T[(kb+2)*256 + tid];
        float w3 = w2T[(kb+3)*256 + tid];
        #pragma unroll
        for (int r = 0; r < 16; ++r) {
            float4 v = hbq[r * 64 + k4];
            a2[r] = fmaf(w0, v.x, a2[r]);
            a2[r] = fmaf(w1, v.y, a2[r]);
            a2[r] = fmaf(w2, v.z, a2[r]);
            a2[r] = fmaf(w3, v.w, a2[r]);
        }
    }
    __syncthreads();
    #pragma unroll
    for (int r = 0; r < 16; ++r) hb[r * HID + tid] = tanh_f(a2[r]);
    __syncthreads();

    // phase C: fo = h2 @ w3.T + b3 (thread covers 8 rows at out-dim tid&127)
    int od = tid & 127;
    int r0 = (tid >> 7) * 8;
    float a3[8];
    #pragma unroll
    for (int rr = 0; rr < 8; ++rr) a3[rr] = b3o;
    for (int k4 = 0; k4 < 64; ++k4) {
        int kb = k4 * 4;
        float w0 = w3T[(kb+0)*LL + od];
        float w1 = w3T[(kb+1)*LL + od];
        float w2 = w3T[(kb+2)*LL + od];
        float w3 = w3T[(kb+3)*LL + od];
        #pragma unroll
        for (int rr = 0; rr < 8; ++rr) {
            float4 v = hbq[(r0 + rr) * 64 + k4];
            a3[rr] = fmaf(w0, v.x, a3[rr]);
            a3[rr] = fmaf(w1, v.y, a3[rr]);
            a3[rr] = fmaf(w2, v.z, a3[rr]);
            a3[rr] = fmaf(w3, v.w, a3[rr]);
        }
    }
    #pragma unroll
    for (int rr = 0; rr < 8; ++rr) fo[(r0 + rr) * LL + od] = a3[rr];
    __syncthreads();
}

__global__ __launch_bounds__(256, 4) void ode_head_k(
    const float* __restrict__ zinit,
    const float* __restrict__ w1T, const float* __restrict__ w2T, const float* __restrict__ w3T,
    const float* __restrict__ b1, const float* __restrict__ b2, const float* __restrict__ b3,
    const float* __restrict__ tembs,
    const float* __restrict__ shw1g, const float* __restrict__ shb1,
    const float* __restrict__ shw2, const float* __restrict__ shb2,
    float* __restrict__ out_haz, float* __restrict__ out_surv, float* __restrict__ out_pg) {

    __shared__ float z  [16 * LL];   // 8KB
    __shared__ float ztl[16 * LL];   // 8KB
    __shared__ float fo [16 * LL];   // 8KB
    __shared__ float hb [16 * HID];  // 16KB   => exactly 40960B total

    int tid = threadIdx.x, blk = blockIdx.x;
    int s = tid & 15, r_h = tid >> 4;
    float b1j = b1[tid], b2j = b2[tid], b3o = b3[tid & 127];
    float w2a = shw2[s], w2b = shw2[16 + s];
    float b1a = shb1[s], b1b = shb1[16 + s];
    float b2s = shb2[0];
    float cum_r = 0.0f;

    float4* zq   = (float4*)z;
    float4* ztlq = (float4*)ztl;
    const float4* foq = (const float4*)fo;
    const float4* wAq = (const float4*)(shw1g + s * LL);
    const float4* wBq = (const float4*)(shw1g + (16 + s) * LL);
    const float4* zrq = (const float4*)(z + r_h * LL);

    {
        const float4* ziq = (const float4*)(zinit + (size_t)blk * 2048);
        zq[2 * tid]     = ziq[2 * tid];
        zq[2 * tid + 1] = ziq[2 * tid + 1];
    }
    __syncthreads();

    const float hh = 1.0f / 47.0f;
    float4 ka0, ka1, z0r, z1r;

    for (int jout = 0; jout <= NSTEP; ++jout) {
        // ---- emit head at current z ----
        {
            float aa = b1a, ab = b1b;
            for (int k4 = 0; k4 < 32; ++k4) {
                float4 zv = zrq[k4];
                float4 va = wAq[k4], vb = wBq[k4];
                aa = fmaf(va.x, zv.x, aa); aa = fmaf(va.y, zv.y, aa);
                aa = fmaf(va.z, zv.z, aa); aa = fmaf(va.w, zv.w, aa);
                ab = fmaf(vb.x, zv.x, ab); ab = fmaf(vb.y, zv.y, ab);
                ab = fmaf(vb.z, zv.z, ab); ab = fmaf(vb.w, zv.w, ab);
            }
            float p = fmaxf(aa, 0.0f) * w2a + fmaxf(ab, 0.0f) * w2b;
            p += __shfl_xor(p, 1); p += __shfl_xor(p, 2);
            p += __shfl_xor(p, 4); p += __shfl_xor(p, 8);
            float hz = sigm_f(p + b2s);
            float sv = __expf(cum_r);
            cum_r += __logf(1.0f - hz + 1e-7f);
            if (s == 0) {
                int row = blk * 16 + r_h;
                out_haz [row * NHZ + jout] = hz;
                out_surv[row * NHZ + jout] = sv;
                if (jout == NHZ - 1) out_pg[row] = 1.0f - sv;
            }
        }
        if (jout == NSTEP) break;

        // ---- one RK4 step jout/47 -> (jout+1)/47 ----
        ode_f(z, hb, fo, w1T, w2T, w3T, tembs + (2 * jout) * 8, b1j, b2j, b3o, tid);   // k1
        {
            float4 f0 = foq[2 * tid], f1 = foq[2 * tid + 1];
            z0r = zq[2 * tid]; z1r = zq[2 * tid + 1];
            ka0 = f0; ka1 = f1;
            ztlq[2 * tid]     = axpy4(0.5f * hh, f0, z0r);
            ztlq[2 * tid + 1] = axpy4(0.5f * hh, f1, z1r);
        }
        __syncthreads();
        ode_f(ztl, hb, fo, w1T, w2T, w3T, tembs + (2 * jout + 1) * 8, b1j, b2j, b3o, tid); // k2
        {
            float4 f0 = foq[2 * tid], f1 = foq[2 * tid + 1];
            ka0 = axpy4(2.0f, f0, ka0); ka1 = axpy4(2.0f, f1, ka1);
            ztlq[2 * tid]     = axpy4(0.5f * hh, f0, z0r);
            ztlq[2 * tid + 1] = axpy4(0.5f * hh, f1, z1r);
        }
        __syncthreads();
        ode_f(ztl, hb, fo, w1T, w2T, w3T, tembs + (2 * jout + 1) * 8, b1j, b2j, b3o, tid); // k3
        {
            float4 f0 = foq[2 * tid], f1 = foq[2 * tid + 1];
            ka0 = axpy4(2.0f, f0, ka0); ka1 = axpy4(2.0f, f1, ka1);
            ztlq[2 * tid]     = axpy4(hh, f0, z0r);
            ztlq[2 * tid + 1] = axpy4(hh, f1, z1r);
        }
        __syncthreads();
        ode_f(ztl, hb, fo, w1T, w2T, w3T, tembs + (2 * jout + 2) * 8, b1j, b2j, b3o, tid); // k4
        {
            float4 f0 = foq[2 * tid], f1 = foq[2 * tid + 1];
            float s6 = hh / 6.0f;
            zq[2 * tid]     = make_float4(fmaf(s6, ka0.x + f0.x, z0r.x), fmaf(s6, ka0.y + f0.y, z0r.y),
                                          fmaf(s6, ka0.z + f0.z, z0r.z), fmaf(s6, ka0.w + f0.w, z0r.w));
            zq[2 * tid + 1] = make_float4(fmaf(s6, ka1.x + f1.x, z1r.x), fmaf(s6, ka1.y + f1.y, z1r.y),
                                          fmaf(s6, ka1.z + f1.z, z1r.z), fmaf(s6, ka1.w + f1.w, z1r.w));
        }
        __syncthreads();
    }
}

// ---------------- launch ----------------

extern "C" void kernel_launch(void* const* d_in, const int* in_sizes, int n_in,
                              void* d_out, int out_size, void* d_ws, size_t ws_size,
                              hipStream_t stream) {
    const float* X        = (const float*)d_in[0];
    const float* Mask     = (const float*)d_in[1];
    const float* gru_w_ih = (const float*)d_in[2];
    const float* gru_w_hh = (const float*)d_in[3];
    const float* gru_b_ih = (const float*)d_in[4];
    const float* gru_b_hh = (const float*)d_in[5];
    const float* z0_w     = (const float*)d_in[6];
    const float* z0_b     = (const float*)d_in[7];
    const float* tproj_w  = (const float*)d_in[8];
    const float* tproj_b  = (const float*)d_in[9];
    const float* ode_w1   = (const float*)d_in[10];
    const float* ode_b1   = (const float*)d_in[11];
    const float* ode_w2   = (const float*)d_in[12];
    const float* ode_b2   = (const float*)d_in[13];
    const float* ode_w3   = (const float*)d_in[14];
    const float* ode_b3   = (const float*)d_in[15];
    const float* sh_w1    = (const float*)d_in[16];
    const float* sh_b1    = (const float*)d_in[17];
    const float* sh_w2    = (const float*)d_in[18];
    const float* sh_b2    = (const float*)d_in[19];

    float* ws    = (float*)d_ws;
    float* w_ihT = ws;                    // 64*768    = 49152
    float* w_hhT = w_ihT + 49152;         // 256*768   = 196608
    float* z0_wT = w_hhT + 196608;        // 256*256   = 65536
    float* w1T   = z0_wT + 65536;         // 136*256   = 34816
    float* w2T   = w1T   + 34816;         // 256*256   = 65536
    float* w3T   = w2T   + 65536;         // 256*128   = 32768
    float* tembs = w3T   + 32768;         // 95*8      = 760

    float* out      = (float*)d_out;
    float* out_haz  = out;                              // 4096*48
    float* out_surv = out + 196608;                     // 4096*48
    float* out_mean = out + 393216;                     // 4096*128
    float* out_lv   = out + 917504;                     // 4096*128
    float* out_pg   = out + 1441792;                    // 4096

    transpose_k<<<(768*64  + 255) / 256, 256, 0, stream>>>(gru_w_ih, w_ihT, 768, 64);
    transpose_k<<<(768*256 + 255) / 256, 256, 0, stream>>>(gru_w_hh, w_hhT, 768, 256);
    transpose_k<<<(256*256 + 255) / 256, 256, 0, stream>>>(z0_w,     z0_wT, 256, 256);
    transpose_k<<<(256*136 + 255) / 256, 256, 0, stream>>>(ode_w1,   w1T,   256, 136);
    transpose_k<<<(256*256 + 255) / 256, 256, 0, stream>>>(ode_w2,   w2T,   256, 256);
    transpose_k<<<(128*256 + 255) / 256, 256, 0, stream>>>(ode_w3,   w3T,   128, 256);
    temb_k<<<2, 64, 0, stream>>>(tproj_w, tproj_b, tembs);

    gru_k<<<BB / 16, 256, 0, stream>>>(X, Mask, w_ihT, w_hhT, gru_b_ih, gru_b_hh,
                                       z0_wT, z0_b, out_mean, out_lv);

    ode_head_k<<<BB / 16, 256, 0, stream>>>(out_mean, w1T, w2T, w3T,
                                            ode_b1, ode_b2, ode_b3, tembs,
                                            sh_w1, sh_b1, sh_w2, sh_b2,
                                            out_haz, out_surv, out_pg);
}